// Round 4
// baseline (86.919 us; speedup 1.0000x reference)
//
#include <hip/hip_runtime.h>

// Soft histogram via quantization table:
//   hist[b,c,j] = (1/P) * sum_pixels f_j(x),  f_j(x) = k_j(x)/(sum_j k_j(x)+1e-12)
// f depends only on x -> quantize x into NQ cells, precompute f at cell centers,
// reduce to integer histogram + tiny contraction. Measured absmax 1.2e-4 vs 3.3e-4 tol.
//
// R2: two dispatches; disjoint partial histograms, no global atomics.
// R3/R4: 1024-thread finalize -> container failed twice. Never again.
// R5: 256-thread finalize + wide unrolls: 90.0 -> 75.7 us.
// R6: finalize was per-CU-bandwidth-bound (24 blocks = 24 CUs pulling 384 KB
//     each through one L2/L3 port). Split finalize 8-way per image ->
//     192 blocks, 8x less traffic per block; last-block-per-image (atomic
//     ticket, fenced) merges the 8 partials and normalizes. Still 2 dispatches,
//     still 256-thread blocks.

#define NQ      1024
#define NBINS   64
#define NIMG    24            // B*C = 8*3
#define IMG_PIX (512 * 512)   // 262144 pixels per (b,c) image
#define BPI     32            // count blocks per image
#define CNT_BLOCKS (NIMG * BPI)        // 768
#define TBL_BLOCKS (NQ / 4)            // 256 (4 quant cells per 256-thread block)
#define SLICES  8                      // finalize blocks per image
#define SLICE_Q (NQ / SLICES)          // 128 q-cells per finalize block

// ---- K1: fused count (blocks 0..767) + table build (blocks 768..1023) ----
__global__ __launch_bounds__(256) void soft_hist_k1(
    const float* __restrict__ x, const float* __restrict__ centers,
    float* __restrict__ table, unsigned int* __restrict__ parts,
    unsigned int* __restrict__ tickets)
{
    const int bid = blockIdx.x;
    const int t   = threadIdx.x;

    if (bid < CNT_BLOCKS) {
        // ---- per-(image,slice) histogram over NQ quant cells ----
        __shared__ unsigned int h[NQ];
        #pragma unroll
        for (int k = 0; k < NQ / 256; ++k) h[t + k * 256] = 0u;
        __syncthreads();

        // Block covers 2048 float4 (8192 pixels), contiguous 32 KB chunk.
        const float4* x4 = (const float4*)x + (size_t)bid * (IMG_PIX / 4 / BPI);

        // Prefetch all 8 float4 into registers -> 8 HBM loads in flight.
        float4 v[8];
        #pragma unroll
        for (int r = 0; r < 8; ++r) v[r] = x4[r * 256 + t];

        #pragma unroll
        for (int r = 0; r < 8; ++r) {
            const float4 p = v[r];
            int q0 = (int)(p.x * (float)NQ); q0 = q0 < 0 ? 0 : (q0 > NQ - 1 ? NQ - 1 : q0);
            int q1 = (int)(p.y * (float)NQ); q1 = q1 < 0 ? 0 : (q1 > NQ - 1 ? NQ - 1 : q1);
            int q2 = (int)(p.z * (float)NQ); q2 = q2 < 0 ? 0 : (q2 > NQ - 1 ? NQ - 1 : q2);
            int q3 = (int)(p.w * (float)NQ); q3 = q3 < 0 ? 0 : (q3 > NQ - 1 ? NQ - 1 : q3);
            atomicAdd(&h[q0], 1u);
            atomicAdd(&h[q1], 1u);
            atomicAdd(&h[q2], 1u);
            atomicAdd(&h[q3], 1u);
        }
        __syncthreads();

        // Plain coalesced store of this block's partial histogram (disjoint slot).
        unsigned int* dst = parts + (size_t)bid * NQ;
        #pragma unroll
        for (int k = 0; k < NQ / 256; ++k) dst[t + k * 256] = h[t + k * 256];
    } else {
        // First table block also zero-inits the finalize tickets (ws is poisoned).
        if (bid == CNT_BLOCKS && t < NIMG) tickets[t] = 0u;

        // ---- table[q][j] = normalized Gaussian kernel at quant-cell center q ----
        const int lane = t & 63;                       // bin (64 bins == 1 wave)
        const int q    = (bid - CNT_BLOCKS) * 4 + (t >> 6);
        const float cq = ((float)q + 0.5f) * (1.0f / (float)NQ);
        // (x - c)/(SIGMA + 1e-12); 0.02 + 1e-12 rounds to 0.02f in fp32
        const float d  = (cq - centers[lane]) * 50.0f;
        const float e  = expf(-0.5f * d * d);
        float s = e;
        #pragma unroll
        for (int off = 32; off > 0; off >>= 1) s += __shfl_xor(s, off, 64);
        table[q * NBINS + lane] = e / (s + 1e-12f);
    }
}

// ---- K2: 8 blocks per image; each contracts a 128-q slice; last block merges.
__global__ __launch_bounds__(256) void soft_hist_final(
    const unsigned int* __restrict__ parts, const float* __restrict__ table,
    float* gpart, unsigned int* tickets, float* __restrict__ out)
{
    __shared__ float sh[2 * SLICE_Q];
    __shared__ float tf[SLICE_Q];
    __shared__ float part[4][NBINS];
    __shared__ unsigned int is_last;

    const int t   = threadIdx.x;
    const int img = blockIdx.x / SLICES;
    const int k   = blockIdx.x % SLICES;       // q-slice index

    // Phase 1: tf[c] = sum over 32 partials of cell q = k*128 + c.
    // Thread t: cell c = t&127, partial-half h = t>>7 -> 16 independent loads.
    {
        const int c = t & (SLICE_Q - 1);
        const int h = t >> 7;
        const unsigned int* src = parts + (size_t)img * BPI * NQ
                                 + (size_t)(h * 16) * NQ + (k * SLICE_Q + c);
        unsigned int s = 0;
        #pragma unroll
        for (int b = 0; b < 16; ++b) s += src[(size_t)b * NQ];
        sh[h * SLICE_Q + c] = (float)s;
    }
    __syncthreads();
    if (t < SLICE_Q) tf[t] = sh[t] + sh[SLICE_Q + t];
    __syncthreads();

    // Phase 2: contraction over this slice. Group g (of 4) covers 32 q's;
    // lane j = bin. 32 fully-unrolled coalesced 256B table reads in flight.
    const int j = t & 63;
    const int g = t >> 6;
    float acc = 0.0f;
    const float* tb = table + (size_t)(k * SLICE_Q + g * 32) * NBINS + j;
    #pragma unroll
    for (int qq = 0; qq < 32; ++qq)
        acc += tb[(size_t)qq * NBINS] * tf[g * 32 + qq];   // tf read is wave-broadcast
    part[g][j] = acc;
    __syncthreads();

    // Write this slice's 64-float partial.
    if (t < NBINS)
        gpart[(size_t)(img * SLICES + k) * NBINS + t]
            = part[0][t] + part[1][t] + part[2][t] + part[3][t];

    // Release partial, grab ticket; last block of the image finalizes.
    __threadfence();
    if (t == 0) {
        const unsigned int old = atomicAdd(&tickets[img], 1u);
        is_last = (old == SLICES - 1) ? 1u : 0u;
    }
    __syncthreads();
    if (!is_last) return;
    __threadfence();   // acquire: make other slices' gpart writes visible

    if (t < NBINS) {
        const float* gp = gpart + (size_t)img * SLICES * NBINS + t;
        float hsum = 0.0f;
        #pragma unroll
        for (int kk = 0; kk < SLICES; ++kk) hsum += gp[(size_t)kk * NBINS];
        const float hm = hsum * (1.0f / (float)IMG_PIX);     // mean over pixels
        float ss = hm;
        #pragma unroll
        for (int off = 32; off > 0; off >>= 1) ss += __shfl_xor(ss, off, 64);
        out[img * NBINS + t] = hm / (ss + 1e-12f);           // per-image normalize
    }
}

extern "C" void kernel_launch(void* const* d_in, const int* in_sizes, int n_in,
                              void* d_out, int out_size, void* d_ws, size_t ws_size,
                              hipStream_t stream)
{
    const float* x       = (const float*)d_in[0];   // (8,3,512,512) fp32
    const float* centers = (const float*)d_in[1];   // (64,) fp32
    float* out           = (float*)d_out;           // (8,3,64) fp32

    char* ws = (char*)d_ws;
    float*        table   = (float*)ws;                    // 256 KB
    ws += (size_t)NQ * NBINS * sizeof(float);
    unsigned int* parts   = (unsigned int*)ws;             // 3 MB
    ws += (size_t)CNT_BLOCKS * NQ * sizeof(unsigned int);
    float*        gpart   = (float*)ws;                    // 48 KB
    ws += (size_t)NIMG * SLICES * NBINS * sizeof(float);
    unsigned int* tickets = (unsigned int*)ws;             // 96 B

    soft_hist_k1<<<CNT_BLOCKS + TBL_BLOCKS, 256, 0, stream>>>(
        x, centers, table, parts, tickets);
    soft_hist_final<<<NIMG * SLICES, 256, 0, stream>>>(
        parts, table, gpart, tickets, out);
}

// Round 5
// 74.009 us; speedup vs baseline: 1.1744x; 1.1744x over previous
//
#include <hip/hip_runtime.h>

// Soft histogram via quantization table:
//   hist[b,c,j] = (1/P) * sum_pixels f_j(x),  f_j(x) = k_j(x)/(sum_j k_j(x)+1e-12)
// f depends only on x -> quantize x into NQ cells, precompute f at cell centers,
// reduce to integer histogram + tiny contraction. Measured absmax 1.2e-4 vs 3.3e-4 tol.
//
// R2: two dispatches; disjoint partial histograms, no global atomics.
// R3/R4: 1024-thread finalize -> container failed twice. Never again.
// R5: 256-thread finalize + wide unrolls: 90.0 -> 75.7 us.
// R6: 8-way split finalize with __threadfence: 86.9 us. REGRESSION — device
//     fences on multi-XCD gfx950 = per-block L2 writeback/invalidate x192.
// R7: same 8-way split, fence-FREE: all cross-block traffic through
//     device-scope atomics (coherence point, no cache maintenance).
//     Ordering: atomic returns kept live + __syncthreads (compiler emits
//     s_waitcnt vmcnt(0) before s_barrier) before the ticket atomic.

#define NQ      1024
#define NBINS   64
#define NIMG    24            // B*C = 8*3
#define IMG_PIX (512 * 512)   // 262144 pixels per (b,c) image
#define BPI     32            // count blocks per image
#define CNT_BLOCKS (NIMG * BPI)        // 768
#define TBL_BLOCKS (NQ / 4)            // 256 (4 quant cells per 256-thread block)
#define SLICES  8                      // finalize blocks per image
#define SLICE_Q (NQ / SLICES)          // 128 q-cells per finalize block

// ---- K1: fused count (blocks 0..767) + table build (blocks 768..1023) ----
__global__ __launch_bounds__(256) void soft_hist_k1(
    const float* __restrict__ x, const float* __restrict__ centers,
    float* __restrict__ table, unsigned int* __restrict__ parts,
    float* __restrict__ hist_acc, unsigned int* __restrict__ tickets)
{
    const int bid = blockIdx.x;
    const int t   = threadIdx.x;

    if (bid < CNT_BLOCKS) {
        // ---- per-(image,slice) histogram over NQ quant cells ----
        __shared__ unsigned int h[NQ];
        #pragma unroll
        for (int k = 0; k < NQ / 256; ++k) h[t + k * 256] = 0u;
        __syncthreads();

        // Block covers 2048 float4 (8192 pixels), contiguous 32 KB chunk.
        const float4* x4 = (const float4*)x + (size_t)bid * (IMG_PIX / 4 / BPI);

        // Prefetch all 8 float4 into registers -> 8 HBM loads in flight.
        float4 v[8];
        #pragma unroll
        for (int r = 0; r < 8; ++r) v[r] = x4[r * 256 + t];

        #pragma unroll
        for (int r = 0; r < 8; ++r) {
            const float4 p = v[r];
            int q0 = (int)(p.x * (float)NQ); q0 = q0 < 0 ? 0 : (q0 > NQ - 1 ? NQ - 1 : q0);
            int q1 = (int)(p.y * (float)NQ); q1 = q1 < 0 ? 0 : (q1 > NQ - 1 ? NQ - 1 : q1);
            int q2 = (int)(p.z * (float)NQ); q2 = q2 < 0 ? 0 : (q2 > NQ - 1 ? NQ - 1 : q2);
            int q3 = (int)(p.w * (float)NQ); q3 = q3 < 0 ? 0 : (q3 > NQ - 1 ? NQ - 1 : q3);
            atomicAdd(&h[q0], 1u);
            atomicAdd(&h[q1], 1u);
            atomicAdd(&h[q2], 1u);
            atomicAdd(&h[q3], 1u);
        }
        __syncthreads();

        // Plain coalesced store of this block's partial histogram (disjoint slot).
        unsigned int* dst = parts + (size_t)bid * NQ;
        #pragma unroll
        for (int k = 0; k < NQ / 256; ++k) dst[t + k * 256] = h[t + k * 256];
    } else {
        // First table block zero-inits the accumulator + tickets (ws is
        // poisoned each replay; K1->K2 stream order makes zeros visible).
        if (bid == CNT_BLOCKS) {
            #pragma unroll
            for (int k = 0; k < (NIMG * NBINS) / 256; ++k)
                hist_acc[t + k * 256] = 0.0f;
            if (t < NIMG) tickets[t] = 0u;
        }

        // ---- table[q][j] = normalized Gaussian kernel at quant-cell center q ----
        const int lane = t & 63;                       // bin (64 bins == 1 wave)
        const int q    = (bid - CNT_BLOCKS) * 4 + (t >> 6);
        const float cq = ((float)q + 0.5f) * (1.0f / (float)NQ);
        // (x - c)/(SIGMA + 1e-12); 0.02 + 1e-12 rounds to 0.02f in fp32
        const float d  = (cq - centers[lane]) * 50.0f;
        const float e  = expf(-0.5f * d * d);
        float s = e;
        #pragma unroll
        for (int off = 32; off > 0; off >>= 1) s += __shfl_xor(s, off, 64);
        table[q * NBINS + lane] = e / (s + 1e-12f);
    }
}

// ---- K2: 8 blocks per image; each contracts a 128-q slice and atomically
//      accumulates; the last block per image (ticket) normalizes. No fences.
__global__ __launch_bounds__(256) void soft_hist_final(
    const unsigned int* __restrict__ parts, const float* __restrict__ table,
    float* hist_acc, unsigned int* tickets, float* __restrict__ out)
{
    __shared__ float sh[2 * SLICE_Q];
    __shared__ float tf[SLICE_Q];
    __shared__ float part[4][NBINS];
    __shared__ unsigned int is_last;

    const int t   = threadIdx.x;
    const int img = blockIdx.x / SLICES;
    const int k   = blockIdx.x % SLICES;       // q-slice index

    // Phase 1: tf[c] = sum over 32 partials of cell q = k*128 + c.
    // Thread t: cell c = t&127, partial-half h = t>>7 -> 16 loads in flight.
    {
        const int c = t & (SLICE_Q - 1);
        const int h = t >> 7;
        const unsigned int* src = parts + (size_t)img * BPI * NQ
                                 + (size_t)(h * 16) * NQ + (k * SLICE_Q + c);
        unsigned int s = 0;
        #pragma unroll
        for (int b = 0; b < 16; ++b) s += src[(size_t)b * NQ];
        sh[h * SLICE_Q + c] = (float)s;
    }
    __syncthreads();
    if (t < SLICE_Q) tf[t] = sh[t] + sh[SLICE_Q + t];
    __syncthreads();

    // Phase 2: contraction over this slice. Group g (of 4) covers 32 q's;
    // lane j = bin. 32 fully-unrolled coalesced 256B table reads in flight.
    const int j = t & 63;
    const int g = t >> 6;
    float acc = 0.0f;
    const float* tb = table + (size_t)(k * SLICE_Q + g * 32) * NBINS + j;
    #pragma unroll
    for (int qq = 0; qq < 32; ++qq)
        acc += tb[(size_t)qq * NBINS] * tf[g * 32 + qq];   // tf read is wave-broadcast
    part[g][j] = acc;
    __syncthreads();

    // Accumulate this slice's 64-float partial at the coherence point.
    // Keep the atomic return live so the vmcnt(0) before the next barrier
    // provably covers the RMW completion (release without a fence).
    if (t < NBINS) {
        const float old = atomicAdd(&hist_acc[img * NBINS + t],
                                    part[0][t] + part[1][t] + part[2][t] + part[3][t]);
        asm volatile("" :: "v"(old));
    }
    __syncthreads();   // compiler emits s_waitcnt vmcnt(0) before s_barrier

    if (t == 0)
        is_last = (atomicAdd(&tickets[img], 1u) == SLICES - 1) ? 1u : 0u;
    __syncthreads();
    if (!is_last) return;

    // Last block of this image: coherent read via atomic RMW (+0.0f), then
    // normalize. All 8 slices' adds are complete (their barriers drained
    // vmcnt before their tickets).
    if (t < NBINS) {
        const float hsum = atomicAdd(&hist_acc[img * NBINS + t], 0.0f);
        const float hm   = hsum * (1.0f / (float)IMG_PIX);   // mean over pixels
        float ss = hm;
        #pragma unroll
        for (int off = 32; off > 0; off >>= 1) ss += __shfl_xor(ss, off, 64);
        out[img * NBINS + t] = hm / (ss + 1e-12f);           // per-image normalize
    }
}

extern "C" void kernel_launch(void* const* d_in, const int* in_sizes, int n_in,
                              void* d_out, int out_size, void* d_ws, size_t ws_size,
                              hipStream_t stream)
{
    const float* x       = (const float*)d_in[0];   // (8,3,512,512) fp32
    const float* centers = (const float*)d_in[1];   // (64,) fp32
    float* out           = (float*)d_out;           // (8,3,64) fp32

    char* ws = (char*)d_ws;
    float*        table    = (float*)ws;                   // 256 KB
    ws += (size_t)NQ * NBINS * sizeof(float);
    unsigned int* parts    = (unsigned int*)ws;            // 3 MB
    ws += (size_t)CNT_BLOCKS * NQ * sizeof(unsigned int);
    float*        hist_acc = (float*)ws;                   // 6 KB
    ws += (size_t)NIMG * NBINS * sizeof(float);
    unsigned int* tickets  = (unsigned int*)ws;            // 96 B

    soft_hist_k1<<<CNT_BLOCKS + TBL_BLOCKS, 256, 0, stream>>>(
        x, centers, table, parts, hist_acc, tickets);
    soft_hist_final<<<NIMG * SLICES, 256, 0, stream>>>(
        parts, table, hist_acc, tickets, out);
}